// Round 1
// baseline (301.919 us; speedup 1.0000x reference)
//
#include <hip/hip_runtime.h>
#include <hip/hip_bf16.h>
#include <stdint.h>

#define B_ 4
#define S_ 2048
#define D_ 1024
#define H_ 16
#define HD_ 64
#define M_ (B_*S_)   // 8192

typedef __attribute__((ext_vector_type(4))) float f32x4;
typedef __attribute__((ext_vector_type(8))) short bf16x8;   // 8 bf16 for MFMA operand
typedef __attribute__((ext_vector_type(4))) int int4v;
typedef __attribute__((ext_vector_type(8))) unsigned short u16x8;

static __device__ __forceinline__ unsigned short f2bf(float f) {
    union { float f; unsigned u; } v; v.f = f;
    unsigned r = v.u + 0x7FFF + ((v.u >> 16) & 1);
    return (unsigned short)(r >> 16);
}

// ---------------- kernel 0a: X fp32 -> bf16 ----------------
__global__ __launch_bounds__(256) void cvt_x_kernel(const float* __restrict__ x,
                                                    unsigned short* __restrict__ xb) {
    int i = (blockIdx.x * 256 + threadIdx.x) * 4;
    float4 v = *(const float4*)(x + i);
    ushort4 o = make_ushort4(f2bf(v.x), f2bf(v.y), f2bf(v.z), f2bf(v.w));
    *(ushort4*)(xb + i) = o;
}

// ---------------- kernel 0b: W [k][n] fp32 -> Wt [n][k] bf16 (x3) ----------------
__global__ __launch_bounds__(256) void cvt_w_kernel(const float* __restrict__ Wq,
                                                    const float* __restrict__ Wk,
                                                    const float* __restrict__ Wv,
                                                    unsigned short* __restrict__ Wt3) {
    const float* W = (blockIdx.z == 0) ? Wq : ((blockIdx.z == 1) ? Wk : Wv);
    unsigned short* out = Wt3 + (size_t)blockIdx.z * 1024 * 1024;
    __shared__ unsigned short t[64][68];
    int k0 = blockIdx.x * 64, n0 = blockIdx.y * 64;
    int tid = threadIdx.x;
#pragma unroll
    for (int i = 0; i < 4; i++) {
        int c = i * 256 + tid;
        int row = c >> 4, cb = c & 15;
        float4 v = *(const float4*)(W + (size_t)(k0 + row) * 1024 + n0 + cb * 4);
        ushort4 o = make_ushort4(f2bf(v.x), f2bf(v.y), f2bf(v.z), f2bf(v.w));
        *(ushort4*)(&t[row][cb * 4]) = o;
    }
    __syncthreads();
#pragma unroll
    for (int i = 0; i < 2; i++) {
        int c = i * 256 + tid;
        int n = c >> 3, kc = c & 7;
        u16x8 tmp;
#pragma unroll
        for (int j = 0; j < 8; j++) tmp[j] = t[kc * 8 + j][n];
        *(u16x8*)(&out[(size_t)(n0 + n) * 1024 + k0 + kc * 8]) = tmp;
    }
}

// ---------------- kernel 1: QKV GEMM (bf16 MFMA, 128x128 tile, BK=64) ----------------
// C[m][n] = sum_k Xb[m][k] * Wt[n][k] + bias[n]
// z=0 -> Q [B,S,D] bf16 ; z=1 -> K [B,S,D] bf16 ; z=2 -> Vt [B,H,HD,S] bf16
__global__ __launch_bounds__(256) void qkv_gemm_kernel(
    const unsigned short* __restrict__ Xb,
    const unsigned short* __restrict__ Wt3,
    const float* __restrict__ bq, const float* __restrict__ bk, const float* __restrict__ bv,
    unsigned short* __restrict__ Qo, unsigned short* __restrict__ Ko,
    unsigned short* __restrict__ Vt)
{
    int z = blockIdx.z;
    const unsigned short* Wt = Wt3 + (size_t)z * 1048576;
    const float* bias = (z == 0) ? bq : ((z == 1) ? bk : bv);
    int m0 = blockIdx.x * 128, n0 = blockIdx.y * 128;

    __shared__ unsigned short As[128 * 64];  // 16KB, swizzled
    __shared__ unsigned short Bs[128 * 64];

    int tid = threadIdx.x, lane = tid & 63, wave = tid >> 6;
    int wm = wave >> 1, wn = wave & 1;
    int lr = lane & 15, lg = lane >> 4;
    int swzf = (lr & 7) << 4;   // frag-read swizzle (rows differ by mult of 16)

    f32x4 acc[4][4] = {};

    for (int kt = 0; kt < 16; kt++) {
        int kbase = kt * 64;
#pragma unroll
        for (int i = 0; i < 4; i++) {
            int c = i * 256 + tid;
            int row = c >> 3, cb = c & 7;
            int4v av = *(const int4v*)(Xb + (size_t)(m0 + row) * 1024 + kbase + cb * 8);
            int4v bv2 = *(const int4v*)(Wt + (size_t)(n0 + row) * 1024 + kbase + cb * 8);
            int off = row * 128 + ((cb * 16) ^ ((row & 7) << 4));
            *(int4v*)((char*)As + off) = av;
            *(int4v*)((char*)Bs + off) = bv2;
        }
        __syncthreads();
#pragma unroll
        for (int kk = 0; kk < 2; kk++) {
            bf16x8 a[4], bb[4];
#pragma unroll
            for (int mi = 0; mi < 4; mi++)
                a[mi] = *(const bf16x8*)((char*)As + (wm * 64 + mi * 16 + lr) * 128
                                         + ((kk * 64 + lg * 16) ^ swzf));
#pragma unroll
            for (int ni = 0; ni < 4; ni++)
                bb[ni] = *(const bf16x8*)((char*)Bs + (wn * 64 + ni * 16 + lr) * 128
                                          + ((kk * 64 + lg * 16) ^ swzf));
#pragma unroll
            for (int mi = 0; mi < 4; mi++)
#pragma unroll
                for (int ni = 0; ni < 4; ni++)
                    acc[mi][ni] = __builtin_amdgcn_mfma_f32_16x16x32_bf16(a[mi], bb[ni], acc[mi][ni], 0, 0, 0);
        }
        __syncthreads();
    }

    // epilogue.  D layout: col = lane&15, row = (lane>>4)*4 + reg
    if (z < 2) {
        unsigned short* out = (z == 0) ? Qo : Ko;
#pragma unroll
        for (int ni = 0; ni < 4; ni++) {
            int n = n0 + wn * 64 + ni * 16 + lr;
            float bsv = bias[n];
#pragma unroll
            for (int mi = 0; mi < 4; mi++) {
                int mrow = m0 + wm * 64 + mi * 16 + lg * 4;
#pragma unroll
                for (int r = 0; r < 4; r++)
                    out[(size_t)(mrow + r) * 1024 + n] = f2bf(acc[mi][ni][r] + bsv);
            }
        }
    } else {
#pragma unroll
        for (int ni = 0; ni < 4; ni++) {
            int n = n0 + wn * 64 + ni * 16 + lr;
            float bsv = bias[n];
            int h = n >> 6, hd = n & 63;
#pragma unroll
            for (int mi = 0; mi < 4; mi++) {
                int mrow = m0 + wm * 64 + mi * 16 + lg * 4;
                int b = mrow >> 11, s = mrow & 2047;
                ushort4 pk = make_ushort4(f2bf(acc[mi][ni][0] + bsv),
                                          f2bf(acc[mi][ni][1] + bsv),
                                          f2bf(acc[mi][ni][2] + bsv),
                                          f2bf(acc[mi][ni][3] + bsv));
                *(ushort4*)(&Vt[((size_t)(b * 16 + h) * 64 + hd) * 2048 + s]) = pk;
            }
        }
    }
}

// ---------------- kernel 2: flash attention ----------------
// grid (S/64, B*H), 256 thr = 4 waves, wave w owns q rows [q0+16w, q0+16w+16)
__global__ __launch_bounds__(256) void attn_kernel(
    const unsigned short* __restrict__ Q,   // [B*S][1024]
    const unsigned short* __restrict__ K,   // [B*S][1024]
    const unsigned short* __restrict__ Vt,  // [B*H*64][2048]
    const float* __restrict__ mask,         // [B][S]
    float* __restrict__ out)                // [B*S][1024] fp32
{
    int q0 = blockIdx.x * 64;
    int bh = blockIdx.y;
    int b = bh >> 4, h = bh & 15;
    int tid = threadIdx.x, lane = tid & 63, w = tid >> 6;
    int lr = lane & 15, lg = lane >> 4;
    int swzf = (lr & 7) << 4;

    __shared__ unsigned short Ks[64 * 64];      // [kv][d], swizzled
    __shared__ unsigned short Vs[64 * 64];      // [hd][kv], swizzled
    __shared__ unsigned short Ps[4][16 * 64];   // per-wave P, swizzled

    // Q fragments, kept in registers for the whole kernel
    const unsigned short* Qrow = Q + (size_t)(b * 2048 + q0 + w * 16 + lr) * 1024 + h * 64;
    bf16x8 aq[2];
    aq[0] = *(const bf16x8*)(Qrow + lg * 8);
    aq[1] = *(const bf16x8*)(Qrow + 32 + lg * 8);

    float mrun[4] = {-1e30f, -1e30f, -1e30f, -1e30f};
    float lrun[4] = {0.f, 0.f, 0.f, 0.f};
    f32x4 oacc[4] = {};   // [hd-block]; row = lg*4+r, col = hb*16+lr

    const unsigned short* Kbp = K + (size_t)b * 2048 * 1024 + h * 64;
    const unsigned short* Vbp = Vt + (size_t)bh * 64 * 2048;
    const float* mb = mask + b * 2048;
    unsigned short* Pw = &Ps[w][0];

    for (int kt = 0; kt < 32; kt++) {
        int kv0 = kt * 64;
        __syncthreads();   // previous iter's LDS reads complete
#pragma unroll
        for (int i = 0; i < 2; i++) {
            int c = i * 256 + tid;
            int row = c >> 3, cb = c & 7;
            int4v kvv = *(const int4v*)(Kbp + (size_t)(kv0 + row) * 1024 + cb * 8);
            int4v vvv = *(const int4v*)(Vbp + (size_t)row * 2048 + kv0 + cb * 8);
            int off = row * 128 + ((cb * 16) ^ ((row & 7) << 4));
            *(int4v*)((char*)Ks + off) = kvv;
            *(int4v*)((char*)Vs + off) = vvv;
        }
        __syncthreads();

        // S = Q K^T   (16 q rows x 64 kv cols per wave)
        f32x4 sacc[4] = {};
#pragma unroll
        for (int nb = 0; nb < 4; nb++) {
            int row = nb * 16 + lr;
#pragma unroll
            for (int ks = 0; ks < 2; ks++) {
                bf16x8 bk_ = *(const bf16x8*)((char*)Ks + row * 128 + ((ks * 64 + lg * 16) ^ swzf));
                sacc[nb] = __builtin_amdgcn_mfma_f32_16x16x32_bf16(aq[ks], bk_, sacc[nb], 0, 0, 0);
            }
        }

        // online softmax (rows lg*4+r, cols nb*16+lr)
        float mval[4];
#pragma unroll
        for (int nb = 0; nb < 4; nb++) mval[nb] = mb[kv0 + nb * 16 + lr];
        float p[4][4];
#pragma unroll
        for (int r = 0; r < 4; r++) {
            float sv[4];
            float tmax = -1e30f;
#pragma unroll
            for (int nb = 0; nb < 4; nb++) {
                sv[nb] = sacc[nb][r] * 0.125f + mval[nb];
                tmax = fmaxf(tmax, sv[nb]);
            }
            tmax = fmaxf(tmax, __shfl_xor(tmax, 1));
            tmax = fmaxf(tmax, __shfl_xor(tmax, 2));
            tmax = fmaxf(tmax, __shfl_xor(tmax, 4));
            tmax = fmaxf(tmax, __shfl_xor(tmax, 8));
            float mnew = fmaxf(mrun[r], tmax);
            float alpha = __expf(mrun[r] - mnew);
            mrun[r] = mnew;
            float rsum = 0.f;
#pragma unroll
            for (int nb = 0; nb < 4; nb++) {
                float pv = __expf(sv[nb] - mnew);
                p[nb][r] = pv;
                rsum += pv;
            }
            rsum += __shfl_xor(rsum, 1);
            rsum += __shfl_xor(rsum, 2);
            rsum += __shfl_xor(rsum, 4);
            rsum += __shfl_xor(rsum, 8);
            lrun[r] = lrun[r] * alpha + rsum;
#pragma unroll
            for (int hb = 0; hb < 4; hb++) oacc[hb][r] *= alpha;
        }

        // P -> LDS (bf16, swizzled), per-wave region
#pragma unroll
        for (int r = 0; r < 4; r++) {
            int row = lg * 4 + r;
#pragma unroll
            for (int nb = 0; nb < 4; nb++) {
                int colb = (nb * 16 + lr) * 2;
                *(unsigned short*)((char*)Pw + row * 128 + (colb ^ ((row & 7) << 4))) = f2bf(p[nb][r]);
            }
        }
        __syncthreads();   // P visible (and K reads done)

        // O += P V
#pragma unroll
        for (int ks = 0; ks < 2; ks++) {
            bf16x8 ap = *(const bf16x8*)((char*)Pw + lr * 128 + ((ks * 64 + lg * 16) ^ swzf));
#pragma unroll
            for (int hb = 0; hb < 4; hb++) {
                int row = hb * 16 + lr;
                bf16x8 bv_ = *(const bf16x8*)((char*)Vs + row * 128 + ((ks * 64 + lg * 16) ^ swzf));
                oacc[hb] = __builtin_amdgcn_mfma_f32_16x16x32_bf16(ap, bv_, oacc[hb], 0, 0, 0);
            }
        }
    }

    // epilogue: out[b][s][h*64+hd] = oacc / lrun
    float* outp = out + (size_t)(b * 2048 + q0 + w * 16) * 1024 + h * 64;
#pragma unroll
    for (int hb = 0; hb < 4; hb++) {
        int col = hb * 16 + lr;
#pragma unroll
        for (int r = 0; r < 4; r++) {
            int row = lg * 4 + r;
            outp[(size_t)row * 1024 + col] = oacc[hb][r] / lrun[r];
        }
    }
}

extern "C" void kernel_launch(void* const* d_in, const int* in_sizes, int n_in,
                              void* d_out, int out_size, void* d_ws, size_t ws_size,
                              hipStream_t stream) {
    const float* hs   = (const float*)d_in[0];
    const float* mask = (const float*)d_in[1];
    const float* Wq   = (const float*)d_in[2];
    const float* bq   = (const float*)d_in[3];
    const float* Wk   = (const float*)d_in[4];
    const float* bk   = (const float*)d_in[5];
    const float* Wv   = (const float*)d_in[6];
    const float* bv   = (const float*)d_in[7];
    float* out = (float*)d_out;

    char* ws = (char*)d_ws;
    unsigned short* Xb  = (unsigned short*)ws;                           // 16 MB
    unsigned short* Wt3 = (unsigned short*)(ws + 16777216);              // 6 MB
    unsigned short* Qb  = (unsigned short*)(ws + 16777216 + 6291456);    // 16 MB
    unsigned short* Kb  = Qb + 8388608;                                  // 16 MB
    unsigned short* Vt  = Kb + 8388608;                                  // 16 MB

    cvt_x_kernel<<<8192, 256, 0, stream>>>(hs, Xb);
    cvt_w_kernel<<<dim3(16, 16, 3), 256, 0, stream>>>(Wq, Wk, Wv, Wt3);
    qkv_gemm_kernel<<<dim3(64, 8, 3), 256, 0, stream>>>(Xb, Wt3, bq, bk, bv, Qb, Kb, Vt);
    attn_kernel<<<dim3(32, 64), 256, 0, stream>>>(Qb, Kb, Vt, mask, out);
}

// Round 2
// 220.822 us; speedup vs baseline: 1.3672x; 1.3672x over previous
//
#include <hip/hip_runtime.h>
#include <hip/hip_bf16.h>
#include <stdint.h>

typedef __attribute__((ext_vector_type(4))) float f32x4;
typedef __attribute__((ext_vector_type(16))) float f32x16;
typedef __attribute__((ext_vector_type(8))) short bf16x8;
typedef __attribute__((ext_vector_type(4))) int int4v;
typedef __attribute__((ext_vector_type(8))) unsigned short u16x8;
typedef unsigned int u32;

static __device__ __forceinline__ unsigned short f2bf(float f) {
    union { float f; unsigned u; } v; v.f = f;
    unsigned r = v.u + 0x7FFF + ((v.u >> 16) & 1);
    return (unsigned short)(r >> 16);
}

static __device__ __forceinline__ u32 cvtpk(float lo, float hi) {
    u32 r;
    asm("v_cvt_pk_bf16_f32 %0, %1, %2" : "=v"(r) : "v"(lo), "v"(hi));
    return r;
}

// ---------------- kernel 0a: X fp32 -> bf16 ----------------
__global__ __launch_bounds__(256) void cvt_x_kernel(const float* __restrict__ x,
                                                    unsigned short* __restrict__ xb) {
    int i = (blockIdx.x * 256 + threadIdx.x) * 4;
    float4 v = *(const float4*)(x + i);
    ushort4 o = make_ushort4(f2bf(v.x), f2bf(v.y), f2bf(v.z), f2bf(v.w));
    *(ushort4*)(xb + i) = o;
}

// ---------------- kernel 0b: W [k][n] fp32 -> Wt [n][k] bf16 (x3) ----------------
__global__ __launch_bounds__(256) void cvt_w_kernel(const float* __restrict__ Wq,
                                                    const float* __restrict__ Wk,
                                                    const float* __restrict__ Wv,
                                                    unsigned short* __restrict__ Wt3) {
    const float* W = (blockIdx.z == 0) ? Wq : ((blockIdx.z == 1) ? Wk : Wv);
    unsigned short* out = Wt3 + (size_t)blockIdx.z * 1024 * 1024;
    __shared__ unsigned short t[64][68];
    int k0 = blockIdx.x * 64, n0 = blockIdx.y * 64;
    int tid = threadIdx.x;
#pragma unroll
    for (int i = 0; i < 4; i++) {
        int c = i * 256 + tid;
        int row = c >> 4, cb = c & 15;
        float4 v = *(const float4*)(W + (size_t)(k0 + row) * 1024 + n0 + cb * 4);
        ushort4 o = make_ushort4(f2bf(v.x), f2bf(v.y), f2bf(v.z), f2bf(v.w));
        *(ushort4*)(&t[row][cb * 4]) = o;
    }
    __syncthreads();
#pragma unroll
    for (int i = 0; i < 2; i++) {
        int c = i * 256 + tid;
        int n = c >> 3, kc = c & 7;
        u16x8 tmp;
#pragma unroll
        for (int j = 0; j < 8; j++) tmp[j] = t[kc * 8 + j][n];
        *(u16x8*)(&out[(size_t)(n0 + n) * 1024 + k0 + kc * 8]) = tmp;
    }
}

// ---------------- kernel 0c: mask reorder (per-lane register order, *8) ----------------
// maskr[((b*32+kt)*2+hi)*32 + kvb*16 + reg] = 8*mask[b][kt*64 + kvb*32 + (reg&3)+8*(reg>>2)+4*hi]
__global__ __launch_bounds__(256) void mask_reorder_kernel(const float* __restrict__ mask,
                                                           float* __restrict__ maskr) {
    int o = blockIdx.x * 256 + threadIdx.x;   // 0..8191
    int reg = o & 15, kvb = (o >> 4) & 1, hi2 = (o >> 5) & 1, kt = (o >> 6) & 31, bb = o >> 11;
    int kv = kt * 64 + kvb * 32 + (reg & 3) + 8 * (reg >> 2) + 4 * hi2;
    maskr[o] = 8.0f * mask[bb * 2048 + kv];
}

// ---------------- kernel 1: QKV GEMM (bf16 MFMA, 128x128 tile, BK=64) ----------------
__global__ __launch_bounds__(256) void qkv_gemm_kernel(
    const unsigned short* __restrict__ Xb,
    const unsigned short* __restrict__ Wt3,
    const float* __restrict__ bq, const float* __restrict__ bk, const float* __restrict__ bv,
    unsigned short* __restrict__ Qo, unsigned short* __restrict__ Ko,
    unsigned short* __restrict__ Vt)
{
    int z = blockIdx.z;
    const unsigned short* Wt = Wt3 + (size_t)z * 1048576;
    const float* bias = (z == 0) ? bq : ((z == 1) ? bk : bv);
    int m0 = blockIdx.x * 128, n0 = blockIdx.y * 128;

    __shared__ unsigned short As[128 * 64];
    __shared__ unsigned short Bs[128 * 64];

    int tid = threadIdx.x, lane = tid & 63, wave = tid >> 6;
    int wm = wave >> 1, wn = wave & 1;
    int lr = lane & 15, lg = lane >> 4;
    int swzf = (lr & 7) << 4;

    f32x4 acc[4][4] = {};

    for (int kt = 0; kt < 16; kt++) {
        int kbase = kt * 64;
#pragma unroll
        for (int i = 0; i < 4; i++) {
            int c = i * 256 + tid;
            int row = c >> 3, cb = c & 7;
            int4v av = *(const int4v*)(Xb + (size_t)(m0 + row) * 1024 + kbase + cb * 8);
            int4v bv2 = *(const int4v*)(Wt + (size_t)(n0 + row) * 1024 + kbase + cb * 8);
            int off = row * 128 + ((cb * 16) ^ ((row & 7) << 4));
            *(int4v*)((char*)As + off) = av;
            *(int4v*)((char*)Bs + off) = bv2;
        }
        __syncthreads();
#pragma unroll
        for (int kk = 0; kk < 2; kk++) {
            bf16x8 a[4], bb[4];
#pragma unroll
            for (int mi = 0; mi < 4; mi++)
                a[mi] = *(const bf16x8*)((char*)As + (wm * 64 + mi * 16 + lr) * 128
                                         + ((kk * 64 + lg * 16) ^ swzf));
#pragma unroll
            for (int ni = 0; ni < 4; ni++)
                bb[ni] = *(const bf16x8*)((char*)Bs + (wn * 64 + ni * 16 + lr) * 128
                                          + ((kk * 64 + lg * 16) ^ swzf));
#pragma unroll
            for (int mi = 0; mi < 4; mi++)
#pragma unroll
                for (int ni = 0; ni < 4; ni++)
                    acc[mi][ni] = __builtin_amdgcn_mfma_f32_16x16x32_bf16(a[mi], bb[ni], acc[mi][ni], 0, 0, 0);
        }
        __syncthreads();
    }

    if (z < 2) {
        unsigned short* out = (z == 0) ? Qo : Ko;
#pragma unroll
        for (int ni = 0; ni < 4; ni++) {
            int n = n0 + wn * 64 + ni * 16 + lr;
            float bsv = bias[n];
#pragma unroll
            for (int mi = 0; mi < 4; mi++) {
                int mrow = m0 + wm * 64 + mi * 16 + lg * 4;
#pragma unroll
                for (int r = 0; r < 4; r++)
                    out[(size_t)(mrow + r) * 1024 + n] = f2bf(acc[mi][ni][r] + bsv);
            }
        }
    } else {
#pragma unroll
        for (int ni = 0; ni < 4; ni++) {
            int n = n0 + wn * 64 + ni * 16 + lr;
            float bsv = bias[n];
            int h = n >> 6, hd = n & 63;
#pragma unroll
            for (int mi = 0; mi < 4; mi++) {
                int mrow = m0 + wm * 64 + mi * 16 + lg * 4;
                int b = mrow >> 11, s = mrow & 2047;
                ushort4 pk = make_ushort4(f2bf(acc[mi][ni][0] + bsv),
                                          f2bf(acc[mi][ni][1] + bsv),
                                          f2bf(acc[mi][ni][2] + bsv),
                                          f2bf(acc[mi][ni][3] + bsv));
                *(ushort4*)(&Vt[((size_t)(b * 16 + h) * 64 + hd) * 2048 + s]) = pk;
            }
        }
    }
}

// ---------------- kernel 2: flash attention, swapped-operand 32x32x16 ----------------
// grid (S/128, B*H), 256 thr = 4 waves; wave w owns q rows [blk*128+w*32, +32)
// lane: ln31 = its q row (col of S^T/O^T); hi = lane>>5 selects kv/hd sub-halves.
__global__ __launch_bounds__(256) void attn_kernel(
    const unsigned short* __restrict__ Q,    // [B*S][1024] bf16
    const unsigned short* __restrict__ K,    // [B*S][1024] bf16
    const unsigned short* __restrict__ Vt,   // [B*H*64][2048] bf16 (V^T per head)
    const float* __restrict__ maskr,         // [B][32][64] reordered, *8
    float* __restrict__ out)                 // [B*S][1024] fp32
{
    __shared__ __align__(16) char smem[16640];  // Ks 8K | Vs 8K | mask 256B
    const int tid = threadIdx.x, lane = tid & 63, w = tid >> 6;
    const int ln31 = lane & 31, hi = lane >> 5;
    const int bh = blockIdx.y, b = bh >> 4, h = bh & 15;
    const int q0 = blockIdx.x * 128 + w * 32;
    const int swz = (ln31 & 7) << 4;
    const float c1 = 0.18033688011112042f;   // 0.125 * log2(e)

    // persistent Q B-frags: col=q=ln31, k(d) = ds*16 + hi*8 + j
    const unsigned short* Qrow = Q + (size_t)(b * 2048 + q0 + ln31) * 1024 + h * 64;
    bf16x8 aq[4];
#pragma unroll
    for (int ds = 0; ds < 4; ds++) aq[ds] = *(const bf16x8*)(Qrow + ds * 16 + hi * 8);

    const unsigned short* Kbp = K + (size_t)b * 2048 * 1024 + h * 64;
    const unsigned short* Vbp = Vt + (size_t)bh * 64 * 2048;
    const float* mbase = maskr + (size_t)b * 2048;

    // staging coords: thread stages rows r0 and r0+32, 16B chunk cb
    const int r0 = tid >> 3, cb = tid & 7;
    const int woff = (cb * 16) ^ ((r0 & 7) << 4);
    char* KsW0 = smem + r0 * 128 + woff;
    char* KsW1 = smem + (r0 + 32) * 128 + woff;
    char* VsW0 = KsW0 + 8192;
    char* VsW1 = KsW1 + 8192;

    f32x16 oacc0 = {}, oacc1 = {};
    float mrun = -1e30f, lrun = 0.f;

    int4v kr0, kr1, vr0, vr1, mr = {};
    {   // prefetch tile 0
        const size_t ko = (size_t)r0 * 1024 + cb * 8;
        kr0 = *(const int4v*)(Kbp + ko);
        kr1 = *(const int4v*)(Kbp + 32 * 1024 + ko);
        vr0 = *(const int4v*)(Vbp + (size_t)r0 * 2048 + cb * 8);
        vr1 = *(const int4v*)(Vbp + (size_t)(r0 + 32) * 2048 + cb * 8);
        if (tid < 16) mr = *(const int4v*)(mbase + tid * 4);
    }

    char* KsL = smem + ln31 * 128;
    char* VsL = smem + 8192 + ln31 * 128;
    const f32x4* mpl = (const f32x4*)(smem + 16384) + hi * 8;

    for (int kt = 0; kt < 32; kt++) {
        __syncthreads();
        *(int4v*)KsW0 = kr0; *(int4v*)KsW1 = kr1;
        *(int4v*)VsW0 = vr0; *(int4v*)VsW1 = vr1;
        if (tid < 16) *(int4v*)(smem + 16384 + tid * 16) = mr;
        __syncthreads();
        if (kt < 31) {   // prefetch next tile (overlaps compute)
            const int kv0 = (kt + 1) * 64;
            const size_t ko = (size_t)(kv0 + r0) * 1024 + cb * 8;
            kr0 = *(const int4v*)(Kbp + ko);
            kr1 = *(const int4v*)(Kbp + 32 * 1024 + ko);
            vr0 = *(const int4v*)(Vbp + (size_t)r0 * 2048 + kv0 + cb * 8);
            vr1 = *(const int4v*)(Vbp + (size_t)(r0 + 32) * 2048 + kv0 + cb * 8);
            if (tid < 16) mr = *(const int4v*)(mbase + (kv0) + tid * 4);
        }

        // ---- S^T = K . Q^T, accumulator pre-loaded with 8*mask ----
        f32x16 st0, st1;
        {
            f32x4 m0 = mpl[0], m1 = mpl[1], m2 = mpl[2], m3 = mpl[3];
            f32x4 m4 = mpl[4], m5 = mpl[5], m6 = mpl[6], m7 = mpl[7];
#pragma unroll
            for (int j = 0; j < 4; j++) {
                st0[j] = m0[j]; st0[4 + j] = m1[j]; st0[8 + j] = m2[j]; st0[12 + j] = m3[j];
                st1[j] = m4[j]; st1[4 + j] = m5[j]; st1[8 + j] = m6[j]; st1[12 + j] = m7[j];
            }
        }
#pragma unroll
        for (int ds = 0; ds < 4; ds++) {
            const int co = (ds * 32 + hi * 16) ^ swz;
            bf16x8 ka0 = *(const bf16x8*)(KsL + co);
            bf16x8 ka1 = *(const bf16x8*)(KsL + 4096 + co);
            st0 = __builtin_amdgcn_mfma_f32_32x32x16_bf16(ka0, aq[ds], st0, 0, 0, 0);
            st1 = __builtin_amdgcn_mfma_f32_32x32x16_bf16(ka1, aq[ds], st1, 0, 0, 0);
        }

        // ---- online softmax (lane-local q row; combine hi-halves via shfl 32) ----
        float mx = st0[0];
#pragma unroll
        for (int j = 1; j < 16; j++) mx = fmaxf(mx, st0[j]);
#pragma unroll
        for (int j = 0; j < 16; j++) mx = fmaxf(mx, st1[j]);
        mx = fmaxf(mx, __shfl_xor(mx, 32));
        const float mnew = fmaxf(mrun, mx);
        const float alpha = __builtin_amdgcn_exp2f((mrun - mnew) * c1);
        mrun = mnew;
        const float mc = mnew * c1;
        float sum = 0.f;
#pragma unroll
        for (int j = 0; j < 16; j++) { float v = __builtin_amdgcn_exp2f(st0[j] * c1 - mc); st0[j] = v; sum += v; }
#pragma unroll
        for (int j = 0; j < 16; j++) { float v = __builtin_amdgcn_exp2f(st1[j] * c1 - mc); st1[j] = v; sum += v; }
        sum += __shfl_xor(sum, 32);
        lrun = lrun * alpha + sum;
#pragma unroll
        for (int j = 0; j < 16; j++) { oacc0[j] *= alpha; oacc1[j] *= alpha; }

        // ---- P pack (cvt_pk) + hi-half exchange + PV: O^T += V^T . P^T ----
#pragma unroll
        for (int s = 0; s < 4; s++) {
            const f32x16& pp = (s & 2) ? st1 : st0;
            const int rA = (s & 1) * 8, rB = rA + 4;
            u32 cl0 = cvtpk(pp[rA + 0], pp[rA + 1]);
            u32 cl1 = cvtpk(pp[rA + 2], pp[rA + 3]);
            u32 ch0 = cvtpk(pp[rB + 0], pp[rB + 1]);
            u32 ch1 = cvtpk(pp[rB + 2], pp[rB + 3]);
            u32 sl0 = __shfl_xor(cl0, 32), sl1 = __shfl_xor(cl1, 32);
            u32 sh0 = __shfl_xor(ch0, 32), sh1 = __shfl_xor(ch1, 32);
            union { u32 u[4]; bf16x8 v; } pb;
            pb.u[0] = hi ? sh0 : cl0;
            pb.u[1] = hi ? sh1 : cl1;
            pb.u[2] = hi ? ch0 : sl0;
            pb.u[3] = hi ? ch1 : sl1;
            const int co = (s * 32 + hi * 16) ^ swz;
            bf16x8 va0 = *(const bf16x8*)(VsL + co);
            bf16x8 va1 = *(const bf16x8*)(VsL + 4096 + co);
            oacc0 = __builtin_amdgcn_mfma_f32_32x32x16_bf16(va0, pb.v, oacc0, 0, 0, 0);
            oacc1 = __builtin_amdgcn_mfma_f32_32x32x16_bf16(va1, pb.v, oacc1, 0, 0, 0);
        }
    }

    // ---- epilogue: O^T -> LDS transpose -> coalesced fp32 stores ----
    __syncthreads();
    const float rl = 1.0f / lrun;
    float* lw = (float*)(smem + w * 4096);   // per-wave 32hd x 32q f32
    const int qp = lane >> 1, hb = (lane & 1) * 16;
#pragma unroll
    for (int p = 0; p < 2; p++) {
        const f32x16& oa = p ? oacc1 : oacc0;
#pragma unroll
        for (int r = 0; r < 16; r++) {
            int hd = (r & 3) + 8 * (r >> 2) + 4 * hi;
            lw[hd * 32 + ln31] = oa[r] * rl;
        }
        float* od = out + (size_t)(b * 2048 + q0 + qp) * 1024 + h * 64 + p * 32 + hb;
#pragma unroll
        for (int c = 0; c < 4; c++) {
            f32x4 o4;
#pragma unroll
            for (int j = 0; j < 4; j++) o4[j] = lw[(hb + c * 4 + j) * 32 + qp];
            *(f32x4*)(od + c * 4) = o4;
        }
    }
}

extern "C" void kernel_launch(void* const* d_in, const int* in_sizes, int n_in,
                              void* d_out, int out_size, void* d_ws, size_t ws_size,
                              hipStream_t stream) {
    const float* hs   = (const float*)d_in[0];
    const float* mask = (const float*)d_in[1];
    const float* Wq   = (const float*)d_in[2];
    const float* bq   = (const float*)d_in[3];
    const float* Wk   = (const float*)d_in[4];
    const float* bk   = (const float*)d_in[5];
    const float* Wv   = (const float*)d_in[6];
    const float* bv   = (const float*)d_in[7];
    float* out = (float*)d_out;

    char* ws = (char*)d_ws;
    unsigned short* Xb  = (unsigned short*)ws;                           // 16 MB
    unsigned short* Wt3 = (unsigned short*)(ws + 16777216);              // 6 MB
    unsigned short* Qb  = (unsigned short*)(ws + 16777216 + 6291456);    // 16 MB
    unsigned short* Kb  = Qb + 8388608;                                  // 16 MB
    unsigned short* Vt  = Kb + 8388608;                                  // 16 MB
    float* maskr = (float*)(ws + 16777216 + 6291456 + 3 * 16777216);     // 32 KB

    cvt_x_kernel<<<8192, 256, 0, stream>>>(hs, Xb);
    cvt_w_kernel<<<dim3(16, 16, 3), 256, 0, stream>>>(Wq, Wk, Wv, Wt3);
    mask_reorder_kernel<<<32, 256, 0, stream>>>(mask, maskr);
    qkv_gemm_kernel<<<dim3(64, 8, 3), 256, 0, stream>>>(Xb, Wt3, bq, bk, bv, Qb, Kb, Vt);
    attn_kernel<<<dim3(16, 64), 256, 0, stream>>>(Qb, Kb, Vt, maskr, out);
}

// Round 4
// 195.906 us; speedup vs baseline: 1.5411x; 1.1272x over previous
//
#include <hip/hip_runtime.h>
#include <hip/hip_bf16.h>
#include <stdint.h>

typedef __attribute__((ext_vector_type(4))) float f32x4;
typedef __attribute__((ext_vector_type(16))) float f32x16;
typedef __attribute__((ext_vector_type(8))) short bf16x8;
typedef __attribute__((ext_vector_type(4))) int int4v;
typedef __attribute__((ext_vector_type(8))) unsigned short u16x8;
typedef unsigned int u32;

static __device__ __forceinline__ unsigned short f2bf(float f) {
    union { float f; unsigned u; } v; v.f = f;
    unsigned r = v.u + 0x7FFF + ((v.u >> 16) & 1);
    return (unsigned short)(r >> 16);
}

static __device__ __forceinline__ u32 cvtpk(float lo, float hi) {
    u32 r;
    asm("v_cvt_pk_bf16_f32 %0, %1, %2" : "=v"(r) : "v"(lo), "v"(hi));
    return r;
}

// v_permlane32_swap_b32 a, b : a_hi <-> b_lo (cross-lane half swap).
// SAFE ONLY when a and b provably hold distinct values (else regalloc may
// coalesce them into one VGPR and the swap degenerates -- round-3 bug).
static __device__ __forceinline__ void pl32swap_u(u32& a, u32& b) {
    asm("v_permlane32_swap_b32 %0, %1" : "+v"(a), "+v"(b));
}

// ---------------- kernel 0a: X fp32 -> bf16 ----------------
__global__ __launch_bounds__(256) void cvt_x_kernel(const float* __restrict__ x,
                                                    unsigned short* __restrict__ xb) {
    int i = (blockIdx.x * 256 + threadIdx.x) * 4;
    float4 v = *(const float4*)(x + i);
    ushort4 o = make_ushort4(f2bf(v.x), f2bf(v.y), f2bf(v.z), f2bf(v.w));
    *(ushort4*)(xb + i) = o;
}

// ---------------- kernel 0b: W [k][n] fp32 -> Wt [n][k] bf16 (x3) ----------------
__global__ __launch_bounds__(256) void cvt_w_kernel(const float* __restrict__ Wq,
                                                    const float* __restrict__ Wk,
                                                    const float* __restrict__ Wv,
                                                    unsigned short* __restrict__ Wt3) {
    const float* W = (blockIdx.z == 0) ? Wq : ((blockIdx.z == 1) ? Wk : Wv);
    unsigned short* out = Wt3 + (size_t)blockIdx.z * 1024 * 1024;
    __shared__ unsigned short t[64][68];
    int k0 = blockIdx.x * 64, n0 = blockIdx.y * 64;
    int tid = threadIdx.x;
#pragma unroll
    for (int i = 0; i < 4; i++) {
        int c = i * 256 + tid;
        int row = c >> 4, cb = c & 15;
        float4 v = *(const float4*)(W + (size_t)(k0 + row) * 1024 + n0 + cb * 4);
        ushort4 o = make_ushort4(f2bf(v.x), f2bf(v.y), f2bf(v.z), f2bf(v.w));
        *(ushort4*)(&t[row][cb * 4]) = o;
    }
    __syncthreads();
#pragma unroll
    for (int i = 0; i < 2; i++) {
        int c = i * 256 + tid;
        int n = c >> 3, kc = c & 7;
        u16x8 tmp;
#pragma unroll
        for (int j = 0; j < 8; j++) tmp[j] = t[kc * 8 + j][n];
        *(u16x8*)(&out[(size_t)(n0 + n) * 1024 + k0 + kc * 8]) = tmp;
    }
}

// ---------------- kernel 0c: mask reorder (per-lane register order, *8) ----------------
__global__ __launch_bounds__(256) void mask_reorder_kernel(const float* __restrict__ mask,
                                                           float* __restrict__ maskr) {
    int o = blockIdx.x * 256 + threadIdx.x;   // 0..8191
    int reg = o & 15, kvb = (o >> 4) & 1, hi2 = (o >> 5) & 1, kt = (o >> 6) & 31, bb = o >> 11;
    int kv = kt * 64 + kvb * 32 + (reg & 3) + 8 * (reg >> 2) + 4 * hi2;
    maskr[o] = 8.0f * mask[bb * 2048 + kv];
}

// ---------------- kernel 1: QKV GEMM (bf16 MFMA, 128x128 tile, BK=64) ----------------
__global__ __launch_bounds__(256) void qkv_gemm_kernel(
    const unsigned short* __restrict__ Xb,
    const unsigned short* __restrict__ Wt3,
    const float* __restrict__ bq, const float* __restrict__ bk, const float* __restrict__ bv,
    unsigned short* __restrict__ Qo, unsigned short* __restrict__ Ko,
    unsigned short* __restrict__ Vt)
{
    int z = blockIdx.z;
    const unsigned short* Wt = Wt3 + (size_t)z * 1048576;
    const float* bias = (z == 0) ? bq : ((z == 1) ? bk : bv);
    int m0 = blockIdx.x * 128, n0 = blockIdx.y * 128;

    __shared__ unsigned short As[128 * 64];
    __shared__ unsigned short Bs[128 * 64];

    int tid = threadIdx.x, lane = tid & 63, wave = tid >> 6;
    int wm = wave >> 1, wn = wave & 1;
    int lr = lane & 15, lg = lane >> 4;
    int swzf = (lr & 7) << 4;

    f32x4 acc[4][4] = {};

    for (int kt = 0; kt < 16; kt++) {
        int kbase = kt * 64;
#pragma unroll
        for (int i = 0; i < 4; i++) {
            int c = i * 256 + tid;
            int row = c >> 3, cb = c & 7;
            int4v av = *(const int4v*)(Xb + (size_t)(m0 + row) * 1024 + kbase + cb * 8);
            int4v bv2 = *(const int4v*)(Wt + (size_t)(n0 + row) * 1024 + kbase + cb * 8);
            int off = row * 128 + ((cb * 16) ^ ((row & 7) << 4));
            *(int4v*)((char*)As + off) = av;
            *(int4v*)((char*)Bs + off) = bv2;
        }
        __syncthreads();
#pragma unroll
        for (int kk = 0; kk < 2; kk++) {
            bf16x8 a[4], bb[4];
#pragma unroll
            for (int mi = 0; mi < 4; mi++)
                a[mi] = *(const bf16x8*)((char*)As + (wm * 64 + mi * 16 + lr) * 128
                                         + ((kk * 64 + lg * 16) ^ swzf));
#pragma unroll
            for (int ni = 0; ni < 4; ni++)
                bb[ni] = *(const bf16x8*)((char*)Bs + (wn * 64 + ni * 16 + lr) * 128
                                          + ((kk * 64 + lg * 16) ^ swzf));
#pragma unroll
            for (int mi = 0; mi < 4; mi++)
#pragma unroll
                for (int ni = 0; ni < 4; ni++)
                    acc[mi][ni] = __builtin_amdgcn_mfma_f32_16x16x32_bf16(a[mi], bb[ni], acc[mi][ni], 0, 0, 0);
        }
        __syncthreads();
    }

    if (z < 2) {
        unsigned short* out = (z == 0) ? Qo : Ko;
#pragma unroll
        for (int ni = 0; ni < 4; ni++) {
            int n = n0 + wn * 64 + ni * 16 + lr;
            float bsv = bias[n];
#pragma unroll
            for (int mi = 0; mi < 4; mi++) {
                int mrow = m0 + wm * 64 + mi * 16 + lg * 4;
#pragma unroll
                for (int r = 0; r < 4; r++)
                    out[(size_t)(mrow + r) * 1024 + n] = f2bf(acc[mi][ni][r] + bsv);
            }
        }
    } else {
#pragma unroll
        for (int ni = 0; ni < 4; ni++) {
            int n = n0 + wn * 64 + ni * 16 + lr;
            float bsv = bias[n];
            int h = n >> 6, hd = n & 63;
#pragma unroll
            for (int mi = 0; mi < 4; mi++) {
                int mrow = m0 + wm * 64 + mi * 16 + lg * 4;
                int b = mrow >> 11, s = mrow & 2047;
                ushort4 pk = make_ushort4(f2bf(acc[mi][ni][0] + bsv),
                                          f2bf(acc[mi][ni][1] + bsv),
                                          f2bf(acc[mi][ni][2] + bsv),
                                          f2bf(acc[mi][ni][3] + bsv));
                *(ushort4*)(&Vt[((size_t)(b * 16 + h) * 64 + hd) * 2048 + s]) = pk;
            }
        }
    }
}

// ---------------- kernel 2: flash attention, swapped-operand 32x32x16, dbuf LDS ----------------
// LDS layout: [Ks0:0][Ks1:8192][Vs0:16384][Vs1:24576][m0:32768][m1:33024]
__global__ __launch_bounds__(256) void attn_kernel(
    const unsigned short* __restrict__ Q,    // [B*S][1024] bf16
    const unsigned short* __restrict__ K,    // [B*S][1024] bf16
    const unsigned short* __restrict__ Vt,   // [B*H*64][2048] bf16 (V^T per head)
    const float* __restrict__ maskr,         // [B][32][64] reordered, *8
    float* __restrict__ out)                 // [B*S][1024] fp32
{
    __shared__ __align__(16) char smem[33280];
    const int tid = threadIdx.x, lane = tid & 63, w = tid >> 6;
    const int ln31 = lane & 31, hi = lane >> 5;
    const int bh = blockIdx.y, b = bh >> 4, h = bh & 15;
    const int q0 = blockIdx.x * 128 + w * 32;
    const int swz = (ln31 & 7) << 4;
    const float c1 = 0.18033688011112042f;   // 0.125 * log2(e)
    const float DTHR = 44.361f;              // 8 / c1

    // persistent Q B-frags
    const unsigned short* Qrow = Q + (size_t)(b * 2048 + q0 + ln31) * 1024 + h * 64;
    bf16x8 aq[4];
#pragma unroll
    for (int ds = 0; ds < 4; ds++) aq[ds] = *(const bf16x8*)(Qrow + ds * 16 + hi * 8);

    const unsigned short* Kbp = K + (size_t)b * 2048 * 1024 + h * 64;
    const unsigned short* Vbp = Vt + (size_t)bh * 64 * 2048;

    // staging coords
    const int r0 = tid >> 3, cb = tid & 7;
    const int woff = r0 * 128 + ((cb * 16) ^ ((r0 & 7) << 4));

    const unsigned short* kp = Kbp + (size_t)r0 * 1024 + cb * 8;   // +65536/tile
    const unsigned short* vp = Vbp + (size_t)r0 * 2048 + cb * 8;   // +64/tile
    const float* mp = maskr + (size_t)b * 2048 + tid * 4;          // +64/tile (tid<16)

    f32x16 oacc0 = {}, oacc1 = {};
    float mrun = -1e30f, lrun = 0.f;

    int4v kr0, kr1, vr0, vr1, mr = {};
    // ---- prologue: tile0 -> LDS buf0, tile1 -> regs ----
    kr0 = *(const int4v*)kp; kr1 = *(const int4v*)(kp + 32 * 1024);
    vr0 = *(const int4v*)vp; vr1 = *(const int4v*)(vp + 32 * 2048);
    if (tid < 16) mr = *(const int4v*)mp;
    kp += 65536; vp += 64; mp += 64;
    *(int4v*)(smem + woff) = kr0;
    *(int4v*)(smem + 32 * 128 + woff) = kr1;
    *(int4v*)(smem + 16384 + woff) = vr0;
    *(int4v*)(smem + 16384 + 32 * 128 + woff) = vr1;
    if (tid < 16) *(int4v*)(smem + 32768 + tid * 16) = mr;
    kr0 = *(const int4v*)kp; kr1 = *(const int4v*)(kp + 32 * 1024);
    vr0 = *(const int4v*)vp; vr1 = *(const int4v*)(vp + 32 * 2048);
    if (tid < 16) mr = *(const int4v*)mp;
    kp += 65536; vp += 64; mp += 64;
    __syncthreads();

#pragma unroll 2
    for (int kt = 0; kt < 32; kt++) {
        const int cur = kt & 1;
        const char* KsL = smem + cur * 8192 + ln31 * 128;
        const char* VsL = KsL + 16384;
        const f32x4* mpl = (const f32x4*)(smem + 32768 + cur * 256 + hi * 128);

        // ---- acc init with 8*mask ----
        f32x16 st0, st1;
        {
            f32x4 a0 = mpl[0], a1 = mpl[1], a2 = mpl[2], a3 = mpl[3];
            f32x4 a4 = mpl[4], a5 = mpl[5], a6 = mpl[6], a7 = mpl[7];
#pragma unroll
            for (int j = 0; j < 4; j++) {
                st0[j] = a0[j]; st0[4 + j] = a1[j]; st0[8 + j] = a2[j]; st0[12 + j] = a3[j];
                st1[j] = a4[j]; st1[4 + j] = a5[j]; st1[8 + j] = a6[j]; st1[12 + j] = a7[j];
            }
        }

        // ---- S^T = K . Q^T ----
        __builtin_amdgcn_s_setprio(1);
#pragma unroll
        for (int ds = 0; ds < 4; ds++) {
            const int co = (ds * 32 + hi * 16) ^ swz;
            bf16x8 ka0 = *(const bf16x8*)(KsL + co);
            bf16x8 ka1 = *(const bf16x8*)(KsL + 4096 + co);
            st0 = __builtin_amdgcn_mfma_f32_32x32x16_bf16(ka0, aq[ds], st0, 0, 0, 0);
            st1 = __builtin_amdgcn_mfma_f32_32x32x16_bf16(ka1, aq[ds], st1, 0, 0, 0);
        }
        __builtin_amdgcn_s_setprio(0);

        // ---- online softmax: tree max, defer-max, tree sum ----
        float t16[16];
#pragma unroll
        for (int j = 0; j < 16; j++) t16[j] = fmaxf(st0[j], st1[j]);
#pragma unroll
        for (int stp = 8; stp > 0; stp >>= 1)
#pragma unroll
            for (int j = 0; j < 8; j++) if (j < stp) t16[j] = fmaxf(t16[j], t16[j + stp]);
        float mx = t16[0];
        mx = fmaxf(mx, __shfl_xor(mx, 32));

        if (__any(mx > mrun + DTHR)) {
            const float mnew = fmaxf(mrun, mx);
            const float al = __builtin_amdgcn_exp2f((mrun - mnew) * c1);
            mrun = mnew;
            lrun *= al;
#pragma unroll
            for (int j = 0; j < 16; j++) { oacc0[j] *= al; oacc1[j] *= al; }
        }
        const float mc = mrun * c1;
        float s16[16];
#pragma unroll
        for (int j = 0; j < 16; j++) {
            float v0 = __builtin_amdgcn_exp2f(__builtin_fmaf(st0[j], c1, -mc));
            float v1 = __builtin_amdgcn_exp2f(__builtin_fmaf(st1[j], c1, -mc));
            st0[j] = v0; st1[j] = v1; s16[j] = v0 + v1;
        }
#pragma unroll
        for (int stp = 8; stp > 0; stp >>= 1)
#pragma unroll
            for (int j = 0; j < 8; j++) if (j < stp) s16[j] += s16[j + stp];
        float sum = s16[0];
        sum += __shfl_xor(sum, 32);
        lrun += sum;

        // ---- P pack (cvt_pk + permlane32_swap) + PV: O^T += V^T . P^T ----
        __builtin_amdgcn_s_setprio(1);
#pragma unroll
        for (int s = 0; s < 4; s++) {
            const f32x16& pp = (s & 2) ? st1 : st0;
            const int rA = (s & 1) * 8, rB = rA + 4;
            u32 w0 = cvtpk(pp[rA + 0], pp[rA + 1]);
            u32 w1 = cvtpk(pp[rA + 2], pp[rA + 3]);
            u32 w2 = cvtpk(pp[rB + 0], pp[rB + 1]);
            u32 w3 = cvtpk(pp[rB + 2], pp[rB + 3]);
            pl32swap_u(w0, w2);
            pl32swap_u(w1, w3);
            union { u32 u[4]; bf16x8 v; } pb;
            pb.u[0] = w0; pb.u[1] = w1; pb.u[2] = w2; pb.u[3] = w3;
            const int co = (s * 32 + hi * 16) ^ swz;
            bf16x8 va0 = *(const bf16x8*)(VsL + co);
            bf16x8 va1 = *(const bf16x8*)(VsL + 4096 + co);
            oacc0 = __builtin_amdgcn_mfma_f32_32x32x16_bf16(va0, pb.v, oacc0, 0, 0, 0);
            oacc1 = __builtin_amdgcn_mfma_f32_32x32x16_bf16(va1, pb.v, oacc1, 0, 0, 0);
        }
        __builtin_amdgcn_s_setprio(0);

        // ---- stage tile kt+1 (in regs) -> buf[cur^1]; prefetch tile kt+2 ----
        if (kt < 31) {
            char* base = smem + (cur ^ 1) * 8192;
            *(int4v*)(base + woff) = kr0;
            *(int4v*)(base + 32 * 128 + woff) = kr1;
            *(int4v*)(base + 16384 + woff) = vr0;
            *(int4v*)(base + 16384 + 32 * 128 + woff) = vr1;
            if (tid < 16) *(int4v*)(smem + 32768 + (cur ^ 1) * 256 + tid * 16) = mr;
            if (kt < 30) {
                kr0 = *(const int4v*)kp; kr1 = *(const int4v*)(kp + 32 * 1024);
                vr0 = *(const int4v*)vp; vr1 = *(const int4v*)(vp + 32 * 2048);
                if (tid < 16) mr = *(const int4v*)mp;
                kp += 65536; vp += 64; mp += 64;
            }
        }
        __syncthreads();
    }

    // ---- epilogue: O^T -> LDS transpose -> coalesced fp32 stores ----
    const float rl = 1.0f / lrun;
    float* lw = (float*)(smem + w * 4096);   // per-wave 32hd x 32q f32
    const int qp = lane >> 1, hb = (lane & 1) * 16;
#pragma unroll
    for (int p = 0; p < 2; p++) {
        const f32x16& oa = p ? oacc1 : oacc0;
#pragma unroll
        for (int r = 0; r < 16; r++) {
            int hd = (r & 3) + 8 * (r >> 2) + 4 * hi;
            lw[hd * 32 + ln31] = oa[r] * rl;
        }
        float* od = out + (size_t)(b * 2048 + q0 + qp) * 1024 + h * 64 + p * 32 + hb;
#pragma unroll
        for (int c = 0; c < 4; c++) {
            f32x4 o4;
#pragma unroll
            for (int j = 0; j < 4; j++) o4[j] = lw[(hb + c * 4 + j) * 32 + qp];
            *(f32x4*)(od + c * 4) = o4;
        }
        __syncthreads();
    }
}

extern "C" void kernel_launch(void* const* d_in, const int* in_sizes, int n_in,
                              void* d_out, int out_size, void* d_ws, size_t ws_size,
                              hipStream_t stream) {
    const float* hs   = (const float*)d_in[0];
    const float* mask = (const float*)d_in[1];
    const float* Wq   = (const float*)d_in[2];
    const float* bq   = (const float*)d_in[3];
    const float* Wk   = (const float*)d_in[4];
    const float* bk   = (const float*)d_in[5];
    const float* Wv   = (const float*)d_in[6];
    const float* bv   = (const float*)d_in[7];
    float* out = (float*)d_out;

    char* ws = (char*)d_ws;
    unsigned short* Xb  = (unsigned short*)ws;                           // 16 MB
    unsigned short* Wt3 = (unsigned short*)(ws + 16777216);              // 6 MB
    unsigned short* Qb  = (unsigned short*)(ws + 16777216 + 6291456);    // 16 MB
    unsigned short* Kb  = Qb + 8388608;                                  // 16 MB
    unsigned short* Vt  = Kb + 8388608;                                  // 16 MB
    float* maskr = (float*)(ws + 16777216 + 6291456 + 3 * 16777216);     // 32 KB

    cvt_x_kernel<<<8192, 256, 0, stream>>>(hs, Xb);
    cvt_w_kernel<<<dim3(16, 16, 3), 256, 0, stream>>>(Wq, Wk, Wv, Wt3);
    mask_reorder_kernel<<<32, 256, 0, stream>>>(mask, maskr);
    qkv_gemm_kernel<<<dim3(64, 8, 3), 256, 0, stream>>>(Xb, Wt3, bq, bk, bv, Qb, Kb, Vt);
    attn_kernel<<<dim3(16, 64), 256, 0, stream>>>(Qb, Kb, Vt, maskr, out);
}